// Round 1
// baseline (251.501 us; speedup 1.0000x reference)
//
#include <hip/hip_runtime.h>
#include <hip/hip_bf16.h>

typedef __attribute__((ext_vector_type(4))) float   f32x4;
typedef __attribute__((ext_vector_type(8))) __bf16  bf16x8;
typedef __attribute__((ext_vector_type(4))) __bf16  bf16x4;

#define NB 4
#define SS 2048
#define DD 1024

__device__ __forceinline__ void gload_lds16(const void* g, void* l) {
  __builtin_amdgcn_global_load_lds((const __attribute__((address_space(1))) void*)g,
                                   (__attribute__((address_space(3))) void*)l,
                                   16, 0, 0);
}

// fp32 -> bf16 convert for the three [4,2048,1024] inputs. grid (8192,1,3) x 256
__global__ __launch_bounds__(256) void cvt_in_kernel(
    const float* __restrict__ q, const float* __restrict__ k,
    const float* __restrict__ v, __bf16* __restrict__ X)
{
  const float* src = blockIdx.z == 0 ? q : (blockIdx.z == 1 ? k : v);
  __bf16* dst = X + (size_t)blockIdx.z * (size_t)(NB * SS * DD);
  size_t i = ((size_t)blockIdx.x * 256 + threadIdx.x) * 4;
  float4 f = *(const float4*)&src[i];
  bf16x4 o = { (__bf16)f.x, (__bf16)f.y, (__bf16)f.z, (__bf16)f.w };
  *(bf16x4*)&dst[i] = o;
}

// W[k][n] fp32 -> Wt[n][k] bf16 (transpose+convert); also copy biases. grid (32,32,3) x 256
__global__ __launch_bounds__(256) void prep_w_kernel(
    const float* __restrict__ wq, const float* __restrict__ wk, const float* __restrict__ wv,
    const float* __restrict__ bq, const float* __restrict__ bk, const float* __restrict__ bv,
    __bf16* __restrict__ Wt, float* __restrict__ biasbuf)
{
  const int z = blockIdx.z;
  const float* W  = z == 0 ? wq : (z == 1 ? wk : wv);
  const float* bi = z == 0 ? bq : (z == 1 ? bk : bv);
  __bf16* dst = Wt + (size_t)z * (size_t)(DD * DD);
  const int n0 = blockIdx.x * 32, k0 = blockIdx.y * 32;
  __shared__ float t[32][33];
  const int tx = threadIdx.x & 31, ty = threadIdx.x >> 5;  // ty 0..7
  #pragma unroll
  for (int i = 0; i < 4; i++)
    t[ty + 8 * i][tx] = W[(size_t)(k0 + ty + 8 * i) * DD + n0 + tx];
  __syncthreads();
  #pragma unroll
  for (int i = 0; i < 4; i++)
    dst[(size_t)(n0 + ty + 8 * i) * DD + k0 + tx] = (__bf16)t[tx][ty + 8 * i];
  if (blockIdx.x == 0 && blockIdx.y == 0) {
    #pragma unroll
    for (int i = 0; i < 4; i++)
      biasbuf[z * DD + threadIdx.x + 256 * i] = bi[threadIdx.x + 256 * i];
  }
}

// V[b][s][d] -> Vt[b][d][s], bf16. grid (32, 64, 4) x 256
__global__ __launch_bounds__(256) void transpose_v_kernel(
    const __bf16* __restrict__ V, __bf16* __restrict__ Vt)
{
  const int b = blockIdx.z;
  const int d0 = blockIdx.x * 32, s0 = blockIdx.y * 32;
  __shared__ __bf16 t[32][34];
  const int tx = threadIdx.x & 31, ty = threadIdx.x >> 5;
  const __bf16* src = V + ((size_t)b * SS + s0) * DD + d0;
  #pragma unroll
  for (int i = 0; i < 4; i++)
    t[ty + 8 * i][tx] = src[(size_t)(ty + 8 * i) * DD + tx];
  __syncthreads();
  __bf16* dst = Vt + ((size_t)b * DD + d0) * SS + s0;
  #pragma unroll
  for (int i = 0; i < 4; i++)
    dst[(size_t)(ty + 8 * i) * SS + tx] = t[tx][ty + 8 * i];
}

// in-place row softmax over P[8192][2048] bf16. grid 8192 x 256
__global__ __launch_bounds__(256) void softmax_rows_kernel(__bf16* __restrict__ P)
{
  const int tid = threadIdx.x;
  __bf16* p = P + (size_t)blockIdx.x * SS;
  bf16x8 v = *(const bf16x8*)&p[tid * 8];
  float f[8];
  #pragma unroll
  for (int j = 0; j < 8; j++) f[j] = (float)v[j];
  float m = f[0];
  #pragma unroll
  for (int j = 1; j < 8; j++) m = fmaxf(m, f[j]);
  #pragma unroll
  for (int off = 1; off < 64; off <<= 1) m = fmaxf(m, __shfl_xor(m, off));
  __shared__ float redm[4];
  if ((tid & 63) == 0) redm[tid >> 6] = m;
  __syncthreads();
  m = fmaxf(fmaxf(redm[0], redm[1]), fmaxf(redm[2], redm[3]));
  float s = 0.f;
  #pragma unroll
  for (int j = 0; j < 8; j++) { f[j] = __expf(f[j] - m); s += f[j]; }
  #pragma unroll
  for (int off = 1; off < 64; off <<= 1) s += __shfl_xor(s, off);
  __shared__ float reds[4];
  if ((tid & 63) == 0) reds[tid >> 6] = s;
  __syncthreads();
  s = reds[0] + reds[1] + reds[2] + reds[3];
  const float inv = 1.0f / s;
  bf16x8 o;
  #pragma unroll
  for (int j = 0; j < 8; j++) o[j] = (__bf16)(f[j] * inv);
  *(bf16x8*)&p[tid * 8] = o;
}

// C[M][N] = A[M][K] @ B[N][K]^T (+bias / *scale). 128x128 tile, 4 waves (2x2),
// 16x16x32 bf16 MFMA, global_load_lds staging (m97 structure).
// EPI: 0 = +bias(per z) -> bf16, 1 = *scale -> bf16, 2 = -> fp32
template <int EPI>
__global__ __launch_bounds__(256) void gemm_bt_kernel(
    const __bf16* __restrict__ A, const __bf16* __restrict__ B,
    const float* __restrict__ bias, float scale, void* __restrict__ Cout,
    int M, int N, int K, int lda, int ldb, int ldc,
    long strideA, long strideB, long strideC)
{
  const __bf16* Ab = A + (size_t)blockIdx.z * strideA;
  const __bf16* Bb = B + (size_t)blockIdx.z * strideB;
  const int tid  = threadIdx.x;
  const int lane = tid & 63;
  const int wave = tid >> 6;
  const int wm = wave >> 1, wn = wave & 1;
  const long brow = (long)blockIdx.y * 128, bcol = (long)blockIdx.x * 128;

  __shared__ __bf16 lA[128 * 32];
  __shared__ __bf16 lB[128 * 32];

  f32x4 acc[4][4] = {};

  const __bf16* ga = Ab + (size_t)(brow + (tid >> 2)) * lda + (tid & 3) * 8;
  const __bf16* gb = Bb + (size_t)(bcol + (tid >> 2)) * ldb + (tid & 3) * 8;
  const int ldsOff = tid * 8;
  const int fra = (wm * 64 + (lane & 15)) * 32 + (lane >> 4) * 8;
  const int frb = (wn * 64 + (lane & 15)) * 32 + (lane >> 4) * 8;

  for (int k0 = 0; k0 < K; k0 += 32) {
    gload_lds16(ga + k0,            &lA[ldsOff]);
    gload_lds16(ga + k0 + 64 * (size_t)lda, &lA[ldsOff + 2048]);
    gload_lds16(gb + k0,            &lB[ldsOff]);
    gload_lds16(gb + k0 + 64 * (size_t)ldb, &lB[ldsOff + 2048]);
    __syncthreads();
    bf16x8 af[4], bfr[4];
    #pragma unroll
    for (int mi = 0; mi < 4; mi++) af[mi]  = *(const bf16x8*)&lA[fra + mi * 16 * 32];
    #pragma unroll
    for (int ni = 0; ni < 4; ni++) bfr[ni] = *(const bf16x8*)&lB[frb + ni * 16 * 32];
    #pragma unroll
    for (int mi = 0; mi < 4; mi++)
      #pragma unroll
      for (int ni = 0; ni < 4; ni++)
        acc[mi][ni] = __builtin_amdgcn_mfma_f32_16x16x32_bf16(af[mi], bfr[ni], acc[mi][ni], 0, 0, 0);
    __syncthreads();
  }

  const int cr = (lane >> 4) * 4;
  const int cc = lane & 15;
  #pragma unroll
  for (int mi = 0; mi < 4; mi++) {
    #pragma unroll
    for (int ni = 0; ni < 4; ni++) {
      const long row = brow + wm * 64 + mi * 16 + cr;
      const long col = bcol + wn * 64 + ni * 16 + cc;
      if constexpr (EPI == 2) {
        float* C = (float*)Cout + (size_t)blockIdx.z * strideC;
        #pragma unroll
        for (int e = 0; e < 4; e++) C[(row + e) * (size_t)ldc + col] = acc[mi][ni][e];
      } else if constexpr (EPI == 0) {
        __bf16* C = (__bf16*)Cout + (size_t)blockIdx.z * strideC;
        const float bv = bias[blockIdx.z * DD + col];
        #pragma unroll
        for (int e = 0; e < 4; e++) C[(row + e) * (size_t)ldc + col] = (__bf16)(acc[mi][ni][e] + bv);
      } else {
        __bf16* C = (__bf16*)Cout + (size_t)blockIdx.z * strideC;
        #pragma unroll
        for (int e = 0; e < 4; e++) C[(row + e) * (size_t)ldc + col] = (__bf16)(acc[mi][ni][e] * scale);
      }
    }
  }
}

extern "C" void kernel_launch(void* const* d_in, const int* in_sizes, int n_in,
                              void* d_out, int out_size, void* d_ws, size_t ws_size,
                              hipStream_t stream)
{
  const float* query = (const float*)d_in[0];
  const float* key   = (const float*)d_in[1];
  const float* value = (const float*)d_in[2];
  const float* wq = (const float*)d_in[3];
  const float* bq = (const float*)d_in[4];
  const float* wk = (const float*)d_in[5];
  const float* bk = (const float*)d_in[6];
  const float* wv = (const float*)d_in[7];
  const float* bv = (const float*)d_in[8];

  char* ws = (char*)d_ws;
  // layout (bytes)
  __bf16* Xbf     = (__bf16*)(ws + 0);           // 3 x 8.39M bf16 = 50,331,648 B
  __bf16* Wt      = (__bf16*)(ws + 50331648);    // 3 x 1M bf16    =  6,291,456 B
  float*  biasbuf = (float*)(ws + 56623104);     // 3072 f32       =     12,288 B
  __bf16* Qb      = (__bf16*)(ws + 56635392);    // 16,777,216 B
  __bf16* Kb      = (__bf16*)(ws + 73412608);    // 16,777,216 B
  __bf16* Vb      = (__bf16*)(ws + 90189824);    // 16,777,216 B  (end 106,967,040)
  __bf16* P       = Xbf;   // alias: X dead after projections (33,554,432 B)
  __bf16* Vt      = Qb;    // alias: Q dead after scores GEMM

  dim3 b256(256);

  // 1. convert inputs to bf16
  cvt_in_kernel<<<dim3(8192, 1, 3), b256, 0, stream>>>(query, key, value, Xbf);
  // 2. weights: transpose+convert; biases: copy
  prep_w_kernel<<<dim3(32, 32, 3), b256, 0, stream>>>(wq, wk, wv, bq, bk, bv, Wt, biasbuf);
  // 3. projections: [8192,1024] = X @ Wt^T + bias  (z = q/k/v)
  gemm_bt_kernel<0><<<dim3(8, 64, 3), b256, 0, stream>>>(
      Xbf, Wt, biasbuf, 1.0f, Qb,
      8192, 1024, 1024, 1024, 1024, 1024,
      8388608L, 1048576L, 8388608L);
  // 4. scores: P[b] = Q[b] @ K[b]^T / 32 -> bf16  (z = batch)
  gemm_bt_kernel<1><<<dim3(16, 16, 4), b256, 0, stream>>>(
      Qb, Kb, nullptr, 0.03125f, P,
      2048, 2048, 1024, 1024, 1024, 2048,
      2097152L, 2097152L, 4194304L);
  // 5. V -> Vt (overwrites Q buffer, Q now dead)
  transpose_v_kernel<<<dim3(32, 64, 4), b256, 0, stream>>>(Vb, Vt);
  // 6. softmax rows, in place
  softmax_rows_kernel<<<dim3(8192), b256, 0, stream>>>(P);
  // 7. out[b] = P[b] @ Vt[b]^T -> fp32 d_out
  gemm_bt_kernel<2><<<dim3(8, 16, 4), b256, 0, stream>>>(
      P, Vt, nullptr, 1.0f, d_out,
      2048, 1024, 2048, 2048, 2048, 1024,
      4194304L, 2097152L, 2097152L);

  (void)in_sizes; (void)n_in; (void)out_size; (void)ws_size;
}

// Round 2
// 201.443 us; speedup vs baseline: 1.2485x; 1.2485x over previous
//
#include <hip/hip_runtime.h>
#include <hip/hip_bf16.h>

typedef __attribute__((ext_vector_type(4))) float   f32x4;
typedef __attribute__((ext_vector_type(8))) __bf16  bf16x8;
typedef __attribute__((ext_vector_type(4))) __bf16  bf16x4;

#define NB 4
#define SS 2048
#define DD 1024

__device__ __forceinline__ void gload_lds16(const void* g, void* l) {
  __builtin_amdgcn_global_load_lds((const __attribute__((address_space(1))) void*)g,
                                   (__attribute__((address_space(3))) void*)l,
                                   16, 0, 0);
}

// fp32 -> bf16 convert for the three [4,2048,1024] inputs. grid (8192,1,3) x 256
__global__ __launch_bounds__(256) void cvt_in_kernel(
    const float* __restrict__ q, const float* __restrict__ k,
    const float* __restrict__ v, __bf16* __restrict__ X)
{
  const float* src = blockIdx.z == 0 ? q : (blockIdx.z == 1 ? k : v);
  __bf16* dst = X + (size_t)blockIdx.z * (size_t)(NB * SS * DD);
  size_t i = ((size_t)blockIdx.x * 256 + threadIdx.x) * 4;
  float4 f = *(const float4*)&src[i];
  bf16x4 o = { (__bf16)f.x, (__bf16)f.y, (__bf16)f.z, (__bf16)f.w };
  *(bf16x4*)&dst[i] = o;
}

// W[k][n] fp32 -> Wt[n][k] bf16 (transpose+convert); also copy biases. grid (32,32,3) x 256
__global__ __launch_bounds__(256) void prep_w_kernel(
    const float* __restrict__ wq, const float* __restrict__ wk, const float* __restrict__ wv,
    const float* __restrict__ bq, const float* __restrict__ bk, const float* __restrict__ bv,
    __bf16* __restrict__ Wt, float* __restrict__ biasbuf)
{
  const int z = blockIdx.z;
  const float* W  = z == 0 ? wq : (z == 1 ? wk : wv);
  const float* bi = z == 0 ? bq : (z == 1 ? bk : bv);
  __bf16* dst = Wt + (size_t)z * (size_t)(DD * DD);
  const int n0 = blockIdx.x * 32, k0 = blockIdx.y * 32;
  __shared__ float t[32][33];
  const int tx = threadIdx.x & 31, ty = threadIdx.x >> 5;  // ty 0..7
  #pragma unroll
  for (int i = 0; i < 4; i++)
    t[ty + 8 * i][tx] = W[(size_t)(k0 + ty + 8 * i) * DD + n0 + tx];
  __syncthreads();
  #pragma unroll
  for (int i = 0; i < 4; i++)
    dst[(size_t)(n0 + ty + 8 * i) * DD + k0 + tx] = (__bf16)t[tx][ty + 8 * i];
  if (blockIdx.x == 0 && blockIdx.y == 0) {
    #pragma unroll
    for (int i = 0; i < 4; i++)
      biasbuf[z * DD + threadIdx.x + 256 * i] = bi[threadIdx.x + 256 * i];
  }
}

// V[b][s][d] -> Vt[b][d][s], bf16. grid (32, 64, 4) x 256
__global__ __launch_bounds__(256) void transpose_v_kernel(
    const __bf16* __restrict__ V, __bf16* __restrict__ Vt)
{
  const int b = blockIdx.z;
  const int d0 = blockIdx.x * 32, s0 = blockIdx.y * 32;
  __shared__ __bf16 t[32][34];
  const int tx = threadIdx.x & 31, ty = threadIdx.x >> 5;
  const __bf16* src = V + ((size_t)b * SS + s0) * DD + d0;
  #pragma unroll
  for (int i = 0; i < 4; i++)
    t[ty + 8 * i][tx] = src[(size_t)(ty + 8 * i) * DD + tx];
  __syncthreads();
  __bf16* dst = Vt + ((size_t)b * DD + d0) * SS + s0;
  #pragma unroll
  for (int i = 0; i < 4; i++)
    dst[(size_t)(ty + 8 * i) * SS + tx] = t[tx][ty + 8 * i];
}

// in-place row softmax over P[8192][2048] bf16. grid 8192 x 256
__global__ __launch_bounds__(256) void softmax_rows_kernel(__bf16* __restrict__ P)
{
  const int tid = threadIdx.x;
  __bf16* p = P + (size_t)blockIdx.x * SS;
  bf16x8 v = *(const bf16x8*)&p[tid * 8];
  float f[8];
  #pragma unroll
  for (int j = 0; j < 8; j++) f[j] = (float)v[j];
  float m = f[0];
  #pragma unroll
  for (int j = 1; j < 8; j++) m = fmaxf(m, f[j]);
  #pragma unroll
  for (int off = 1; off < 64; off <<= 1) m = fmaxf(m, __shfl_xor(m, off));
  __shared__ float redm[4];
  if ((tid & 63) == 0) redm[tid >> 6] = m;
  __syncthreads();
  m = fmaxf(fmaxf(redm[0], redm[1]), fmaxf(redm[2], redm[3]));
  float s = 0.f;
  #pragma unroll
  for (int j = 0; j < 8; j++) { f[j] = __expf(f[j] - m); s += f[j]; }
  #pragma unroll
  for (int off = 1; off < 64; off <<= 1) s += __shfl_xor(s, off);
  __shared__ float reds[4];
  if ((tid & 63) == 0) reds[tid >> 6] = s;
  __syncthreads();
  s = reds[0] + reds[1] + reds[2] + reds[3];
  const float inv = 1.0f / s;
  bf16x8 o;
  #pragma unroll
  for (int j = 0; j < 8; j++) o[j] = (__bf16)(f[j] * inv);
  *(bf16x8*)&p[tid * 8] = o;
}

// ---------------------------------------------------------------------------
// 256x256 8-phase counted-vmcnt GEMM: C[M][N] = A[M][K] @ B[N][K]^T
// BK=64, 8 waves (2Mx4N), per-wave 128x64, LDS 128 KiB dbuf, XOR row-swizzle.
// EPI: 0 = +bias(per z) -> bf16, 1 = *scale -> bf16, 2 = -> fp32
// ---------------------------------------------------------------------------

#define A_OFF(BUF, MH) (((BUF)*2 + (MH)) * 16384)
#define B_OFF(BUF, NH) (65536 + ((BUF)*2 + (NH)) * 16384)

#define STAGE_A(BUF, MH, T) do { int t_ = (T); if (t_ >= NT) t_ = 0;            \
  const __bf16* gs_ = Ablk + (size_t)(MH) * (64 * (size_t)lda) + (size_t)t_ * 64; \
  gload_lds16(gs_ + aoff0, smem + A_OFF(BUF, MH) + tid * 16);                    \
  gload_lds16(gs_ + aoff1, smem + A_OFF(BUF, MH) + 8192 + tid * 16); } while (0)

#define STAGE_B(BUF, NH, T) do { int t_ = (T); if (t_ >= NT) t_ = 0;            \
  const __bf16* gs_ = Bblk + (size_t)(NH) * (32 * (size_t)ldb) + (size_t)t_ * 64; \
  gload_lds16(gs_ + boff0, smem + B_OFF(BUF, NH) + tid * 16);                    \
  gload_lds16(gs_ + boff1, smem + B_OFF(BUF, NH) + 8192 + tid * 16); } while (0)

#define DSREAD_A(DST, BUF, MH)                                                  \
  _Pragma("unroll") for (int mi = 0; mi < 4; ++mi) {                            \
    _Pragma("unroll") for (int ks = 0; ks < 2; ++ks)                            \
      DST[mi][ks] = *(const bf16x8*)(smem + A_OFF(BUF, MH) + arb[ks] + mi * 2048); }

#define DSREAD_B(DST, BUF, NH)                                                  \
  _Pragma("unroll") for (int ni = 0; ni < 2; ++ni) {                            \
    _Pragma("unroll") for (int ks = 0; ks < 2; ++ks)                            \
      DST[ni][ks] = *(const bf16x8*)(smem + B_OFF(BUF, NH) + brb[ks] + ni * 2048); }

#define BARRIER_MFMA(AF, BF, MH, NH) do {                                       \
  __builtin_amdgcn_s_barrier();                                                 \
  asm volatile("s_waitcnt lgkmcnt(0)" ::: "memory");                            \
  __builtin_amdgcn_sched_barrier(0);                                            \
  __builtin_amdgcn_s_setprio(1);                                                \
  _Pragma("unroll") for (int mi = 0; mi < 4; ++mi)                              \
  _Pragma("unroll") for (int ni = 0; ni < 2; ++ni)                              \
  _Pragma("unroll") for (int ks = 0; ks < 2; ++ks)                              \
    acc[(MH)*4+mi][(NH)*2+ni] = __builtin_amdgcn_mfma_f32_16x16x32_bf16(        \
        AF[mi][ks], BF[ni][ks], acc[(MH)*4+mi][(NH)*2+ni], 0, 0, 0);            \
  __builtin_amdgcn_s_setprio(0);                                                \
  __builtin_amdgcn_sched_barrier(0);                                            \
  __builtin_amdgcn_s_barrier(); } while (0)

template <int EPI>
__global__ __launch_bounds__(512) void gemm8p_kernel(
    const __bf16* __restrict__ A, const __bf16* __restrict__ B,
    const float* __restrict__ bias, float scale, void* __restrict__ Cout,
    int K, int lda, int ldb, int ldc,
    long strideA, long strideB, long strideC)
{
  extern __shared__ char smem[];

  // XCD-aware bijective swizzle (nwg % 8 == 0 for all our grids)
  const int gx = gridDim.x, gy = gridDim.y;
  const int nwg = gx * gy * gridDim.z;
  int lin = blockIdx.x + gx * (blockIdx.y + gy * blockIdx.z);
  const int cpx = nwg >> 3;
  int swz = (lin & 7) * cpx + (lin >> 3);
  const int bx = swz % gx;
  int rem = swz / gx;
  const int by = rem % gy;
  const int bz = rem / gy;

  const long brow = (long)by * 256, bcol = (long)bx * 256;
  const __bf16* Ablk = A + (size_t)bz * strideA + (size_t)brow * lda;
  const __bf16* Bblk = B + (size_t)bz * strideB + (size_t)bcol * ldb;

  const int tid  = threadIdx.x;
  const int lane = tid & 63;
  const int wid  = tid >> 6;
  const int wm = wid >> 2, wn = wid & 3;
  const int l15 = lane & 15, l4 = lane >> 4;
  const int lx = (lane & 7) << 4;

  const int NT = K >> 6;
  const int niter = NT >> 1;

  // staging source offsets (elements): physical LDS byte -> logical -> global
  int aoff0, aoff1, boff0, boff1;
  #pragma unroll
  for (int i = 0; i < 2; ++i) {
    const int p = i * 8192 + tid * 16;
    const int l = p ^ (((p >> 7) & 7) << 4);
    const int r = p >> 7;            // region row 0..127
    const int kb = l & 127;          // k-bytes within row
    const int av = ((r >> 6) * 128 + (r & 63)) * lda + (kb >> 1);
    const int bv = ((r >> 5) * 64 + (r & 31)) * ldb + (kb >> 1);
    if (i == 0) { aoff0 = av; boff0 = bv; } else { aoff1 = av; boff1 = bv; }
  }

  // ds_read fragment base offsets (bytes, swizzled), per k-step
  int arb[2], brb[2];
  #pragma unroll
  for (int ks = 0; ks < 2; ++ks) {
    arb[ks] = ((((wm * 64 + l15) * 64 + l4 * 8) * 2) + ks * 64) ^ lx;
    brb[ks] = ((((wn * 32 + l15) * 64 + l4 * 8) * 2) + ks * 64) ^ lx;
  }

  f32x4 acc[8][4] = {};
  bf16x8 a0[4][2], a1[4][2], b0[2][2], b1[2][2];

  // prologue: buf0 <- tile0 (all 4 halves), buf1 <- Bh0,Ah0 of tile1
  STAGE_B(0, 0, 0); STAGE_A(0, 0, 0); STAGE_A(0, 1, 0); STAGE_B(0, 1, 0);
  STAGE_B(1, 0, 1); STAGE_A(1, 0, 1);
  asm volatile("s_waitcnt vmcnt(4)" ::: "memory");
  __builtin_amdgcn_s_barrier();

  for (int it = 0; it < niter; ++it) {
    const int tt = it * 2;
    // P1: compute buf0 (mh0, nh0)
    DSREAD_A(a0, 0, 0); DSREAD_B(b0, 0, 0);
    STAGE_A(1, 1, tt + 1);
    BARRIER_MFMA(a0, b0, 0, 0);
    // P2: (mh1, nh0)
    DSREAD_A(a1, 0, 1);
    STAGE_B(1, 1, tt + 1);
    BARRIER_MFMA(a1, b0, 1, 0);
    // P3: (mh0, nh1)
    DSREAD_B(b1, 0, 1);
    STAGE_B(0, 0, tt + 2);
    BARRIER_MFMA(a0, b1, 0, 1);
    // P4: (mh1, nh1) + counted vmcnt
    STAGE_A(0, 0, tt + 2);
    asm volatile("s_waitcnt vmcnt(4)" ::: "memory");
    BARRIER_MFMA(a1, b1, 1, 1);
    // P5: compute buf1 (mh0, nh0)
    DSREAD_A(a0, 1, 0); DSREAD_B(b0, 1, 0);
    STAGE_A(0, 1, tt + 2);
    BARRIER_MFMA(a0, b0, 0, 0);
    // P6: (mh1, nh0)
    DSREAD_A(a1, 1, 1);
    STAGE_B(0, 1, tt + 2);
    BARRIER_MFMA(a1, b0, 1, 0);
    // P7: (mh0, nh1)
    DSREAD_B(b1, 1, 1);
    STAGE_B(1, 0, tt + 3);
    BARRIER_MFMA(a0, b1, 0, 1);
    // P8: (mh1, nh1) + counted vmcnt
    STAGE_A(1, 0, tt + 3);
    asm volatile("s_waitcnt vmcnt(4)" ::: "memory");
    BARRIER_MFMA(a1, b1, 1, 1);
  }

  // epilogue
  const int cr = l4 * 4;
  #pragma unroll
  for (int m = 0; m < 8; ++m) {
    #pragma unroll
    for (int n = 0; n < 4; ++n) {
      const long row = brow + wm * 128 + m * 16 + cr;
      const long col = bcol + wn * 64 + n * 16 + l15;
      if constexpr (EPI == 2) {
        float* C = (float*)Cout + (size_t)bz * strideC;
        #pragma unroll
        for (int e = 0; e < 4; ++e) C[(row + e) * (size_t)ldc + col] = acc[m][n][e];
      } else if constexpr (EPI == 0) {
        __bf16* C = (__bf16*)Cout + (size_t)bz * strideC;
        const float bvv = bias[bz * DD + col];
        #pragma unroll
        for (int e = 0; e < 4; ++e) C[(row + e) * (size_t)ldc + col] = (__bf16)(acc[m][n][e] + bvv);
      } else {
        __bf16* C = (__bf16*)Cout + (size_t)bz * strideC;
        #pragma unroll
        for (int e = 0; e < 4; ++e) C[(row + e) * (size_t)ldc + col] = (__bf16)(acc[m][n][e] * scale);
      }
    }
  }
}

extern "C" void kernel_launch(void* const* d_in, const int* in_sizes, int n_in,
                              void* d_out, int out_size, void* d_ws, size_t ws_size,
                              hipStream_t stream)
{
  const float* query = (const float*)d_in[0];
  const float* key   = (const float*)d_in[1];
  const float* value = (const float*)d_in[2];
  const float* wq = (const float*)d_in[3];
  const float* bq = (const float*)d_in[4];
  const float* wk = (const float*)d_in[5];
  const float* bk = (const float*)d_in[6];
  const float* wv = (const float*)d_in[7];
  const float* bv = (const float*)d_in[8];

  char* ws = (char*)d_ws;
  __bf16* Xbf     = (__bf16*)(ws + 0);           // 50,331,648 B
  __bf16* Wt      = (__bf16*)(ws + 50331648);    //  6,291,456 B
  float*  biasbuf = (float*)(ws + 56623104);     //     12,288 B
  __bf16* Qb      = (__bf16*)(ws + 56635392);    // 16,777,216 B
  __bf16* Kb      = (__bf16*)(ws + 73412608);    // 16,777,216 B
  __bf16* Vb      = (__bf16*)(ws + 90189824);    // 16,777,216 B (end 106,967,040)
  __bf16* P       = Xbf;   // alias: X dead after projections
  __bf16* Vt      = Qb;    // alias: Q dead after scores GEMM

  // allow 128 KiB dynamic LDS
  hipFuncSetAttribute((const void*)gemm8p_kernel<0>, hipFuncAttributeMaxDynamicSharedMemorySize, 131072);
  hipFuncSetAttribute((const void*)gemm8p_kernel<1>, hipFuncAttributeMaxDynamicSharedMemorySize, 131072);
  hipFuncSetAttribute((const void*)gemm8p_kernel<2>, hipFuncAttributeMaxDynamicSharedMemorySize, 131072);

  dim3 b256(256), b512(512);

  cvt_in_kernel<<<dim3(8192, 1, 3), b256, 0, stream>>>(query, key, value, Xbf);
  prep_w_kernel<<<dim3(32, 32, 3), b256, 0, stream>>>(wq, wk, wv, bq, bk, bv, Wt, biasbuf);

  // projections: [8192,1024] = X @ Wt^T + bias  (z = q/k/v), grid 4x32x3 = 384
  gemm8p_kernel<0><<<dim3(4, 32, 3), b512, 131072, stream>>>(
      Xbf, Wt, biasbuf, 1.0f, Qb,
      1024, 1024, 1024, 1024,
      8388608L, 1048576L, 8388608L);
  // scores: P[b] = Q[b] @ K[b]^T / 32 -> bf16, grid 8x8x4 = 256
  gemm8p_kernel<1><<<dim3(8, 8, 4), b512, 131072, stream>>>(
      Qb, Kb, nullptr, 0.03125f, P,
      1024, 1024, 1024, 2048,
      2097152L, 2097152L, 4194304L);

  transpose_v_kernel<<<dim3(32, 64, 4), b256, 0, stream>>>(Vb, Vt);
  softmax_rows_kernel<<<dim3(8192), b256, 0, stream>>>(P);

  // out[b] = P[b] @ Vt[b]^T -> fp32, grid 4x8x4 = 128
  gemm8p_kernel<2><<<dim3(4, 8, 4), b512, 131072, stream>>>(
      P, Vt, nullptr, 1.0f, d_out,
      2048, 2048, 2048, 1024,
      4194304L, 2097152L, 2097152L);

  (void)in_sizes; (void)n_in; (void)out_size; (void)ws_size;
}

// Round 3
// 182.103 us; speedup vs baseline: 1.3811x; 1.1062x over previous
//
#include <hip/hip_runtime.h>
#include <hip/hip_bf16.h>

typedef __attribute__((ext_vector_type(4))) float   f32x4;
typedef __attribute__((ext_vector_type(8))) __bf16  bf16x8;
typedef __attribute__((ext_vector_type(4))) __bf16  bf16x4;

#define NB 4
#define SS 2048
#define DD 1024

__device__ __forceinline__ void gload_lds16(const void* g, void* l) {
  __builtin_amdgcn_global_load_lds((const __attribute__((address_space(1))) void*)g,
                                   (__attribute__((address_space(3))) void*)l,
                                   16, 0, 0);
}

// fp32 -> bf16 convert for the three [4,2048,1024] inputs. grid (8192,1,3) x 256
__global__ __launch_bounds__(256) void cvt_in_kernel(
    const float* __restrict__ q, const float* __restrict__ k,
    const float* __restrict__ v, __bf16* __restrict__ X)
{
  const float* src = blockIdx.z == 0 ? q : (blockIdx.z == 1 ? k : v);
  __bf16* dst = X + (size_t)blockIdx.z * (size_t)(NB * SS * DD);
  size_t i = ((size_t)blockIdx.x * 256 + threadIdx.x) * 4;
  float4 f = *(const float4*)&src[i];
  bf16x4 o = { (__bf16)f.x, (__bf16)f.y, (__bf16)f.z, (__bf16)f.w };
  *(bf16x4*)&dst[i] = o;
}

// W[k][n] fp32 -> Wt[n][k] bf16 (transpose+convert); also copy biases. grid (32,32,3) x 256
__global__ __launch_bounds__(256) void prep_w_kernel(
    const float* __restrict__ wq, const float* __restrict__ wk, const float* __restrict__ wv,
    const float* __restrict__ bq, const float* __restrict__ bk, const float* __restrict__ bv,
    __bf16* __restrict__ Wt, float* __restrict__ biasbuf)
{
  const int z = blockIdx.z;
  const float* W  = z == 0 ? wq : (z == 1 ? wk : wv);
  const float* bi = z == 0 ? bq : (z == 1 ? bk : bv);
  __bf16* dst = Wt + (size_t)z * (size_t)(DD * DD);
  const int n0 = blockIdx.x * 32, k0 = blockIdx.y * 32;
  __shared__ float t[32][33];
  const int tx = threadIdx.x & 31, ty = threadIdx.x >> 5;
  #pragma unroll
  for (int i = 0; i < 4; i++)
    t[ty + 8 * i][tx] = W[(size_t)(k0 + ty + 8 * i) * DD + n0 + tx];
  __syncthreads();
  #pragma unroll
  for (int i = 0; i < 4; i++)
    dst[(size_t)(n0 + ty + 8 * i) * DD + k0 + tx] = (__bf16)t[tx][ty + 8 * i];
  if (blockIdx.x == 0 && blockIdx.y == 0) {
    #pragma unroll
    for (int i = 0; i < 4; i++)
      biasbuf[z * DD + threadIdx.x + 256 * i] = bi[threadIdx.x + 256 * i];
  }
}

// V[b][s][d] -> Vt[b][d][s], bf16. grid (32, 64, 4) x 256
__global__ __launch_bounds__(256) void transpose_v_kernel(
    const __bf16* __restrict__ V, __bf16* __restrict__ Vt)
{
  const int b = blockIdx.z;
  const int d0 = blockIdx.x * 32, s0 = blockIdx.y * 32;
  __shared__ __bf16 t[32][34];
  const int tx = threadIdx.x & 31, ty = threadIdx.x >> 5;
  const __bf16* src = V + ((size_t)b * SS + s0) * DD + d0;
  #pragma unroll
  for (int i = 0; i < 4; i++)
    t[ty + 8 * i][tx] = src[(size_t)(ty + 8 * i) * DD + tx];
  __syncthreads();
  __bf16* dst = Vt + ((size_t)b * DD + d0) * SS + s0;
  #pragma unroll
  for (int i = 0; i < 4; i++)
    dst[(size_t)(ty + 8 * i) * SS + tx] = t[tx][ty + 8 * i];
}

// ---------------------------------------------------------------------------
// 256x256 8-phase counted-vmcnt GEMM (unchanged structure from R2).
// EPI: 1 = store exp(acc*scale) -> bf16 (scores)
// ---------------------------------------------------------------------------

#define A_OFF(BUF, MH) (((BUF)*2 + (MH)) * 16384)
#define B_OFF(BUF, NH) (65536 + ((BUF)*2 + (NH)) * 16384)

#define STAGE_A(BUF, MH, T) do { int t_ = (T); if (t_ >= NT) t_ = 0;            \
  const __bf16* gs_ = Ablk + (size_t)(MH) * (64 * (size_t)lda) + (size_t)t_ * 64; \
  gload_lds16(gs_ + aoff0, smem + A_OFF(BUF, MH) + tid * 16);                    \
  gload_lds16(gs_ + aoff1, smem + A_OFF(BUF, MH) + 8192 + tid * 16); } while (0)

#define STAGE_B(BUF, NH, T) do { int t_ = (T); if (t_ >= NT) t_ = 0;            \
  const __bf16* gs_ = Bblk + (size_t)(NH) * (32 * (size_t)ldb) + (size_t)t_ * 64; \
  gload_lds16(gs_ + boff0, smem + B_OFF(BUF, NH) + tid * 16);                    \
  gload_lds16(gs_ + boff1, smem + B_OFF(BUF, NH) + 8192 + tid * 16); } while (0)

#define DSREAD_A(DST, BUF, MH)                                                  \
  _Pragma("unroll") for (int mi = 0; mi < 4; ++mi) {                            \
    _Pragma("unroll") for (int ks = 0; ks < 2; ++ks)                            \
      DST[mi][ks] = *(const bf16x8*)(smem + A_OFF(BUF, MH) + arb[ks] + mi * 2048); }

#define DSREAD_B(DST, BUF, NH)                                                  \
  _Pragma("unroll") for (int ni = 0; ni < 2; ++ni) {                            \
    _Pragma("unroll") for (int ks = 0; ks < 2; ++ks)                            \
      DST[ni][ks] = *(const bf16x8*)(smem + B_OFF(BUF, NH) + brb[ks] + ni * 2048); }

#define BARRIER_MFMA(AF, BF, MH, NH) do {                                       \
  __builtin_amdgcn_s_barrier();                                                 \
  asm volatile("s_waitcnt lgkmcnt(0)" ::: "memory");                            \
  __builtin_amdgcn_sched_barrier(0);                                            \
  __builtin_amdgcn_s_setprio(1);                                                \
  _Pragma("unroll") for (int mi = 0; mi < 4; ++mi)                              \
  _Pragma("unroll") for (int ni = 0; ni < 2; ++ni)                              \
  _Pragma("unroll") for (int ks = 0; ks < 2; ++ks)                              \
    acc[(MH)*4+mi][(NH)*2+ni] = __builtin_amdgcn_mfma_f32_16x16x32_bf16(        \
        AF[mi][ks], BF[ni][ks], acc[(MH)*4+mi][(NH)*2+ni], 0, 0, 0);            \
  __builtin_amdgcn_s_setprio(0);                                                \
  __builtin_amdgcn_sched_barrier(0);                                            \
  __builtin_amdgcn_s_barrier(); } while (0)

template <int EPI>
__global__ __launch_bounds__(512) void gemm8p_kernel(
    const __bf16* __restrict__ A, const __bf16* __restrict__ B,
    float scale, void* __restrict__ Cout,
    int K, int lda, int ldb, int ldc,
    long strideA, long strideB, long strideC)
{
  extern __shared__ char smem[];

  const int gx = gridDim.x, gy = gridDim.y;
  const int nwg = gx * gy * gridDim.z;
  int lin = blockIdx.x + gx * (blockIdx.y + gy * blockIdx.z);
  const int cpx = nwg >> 3;
  int swz = (lin & 7) * cpx + (lin >> 3);
  const int bx = swz % gx;
  int rem = swz / gx;
  const int by = rem % gy;
  const int bz = rem / gy;

  const long brow = (long)by * 256, bcol = (long)bx * 256;
  const __bf16* Ablk = A + (size_t)bz * strideA + (size_t)brow * lda;
  const __bf16* Bblk = B + (size_t)bz * strideB + (size_t)bcol * ldb;

  const int tid  = threadIdx.x;
  const int lane = tid & 63;
  const int wid  = tid >> 6;
  const int wm = wid >> 2, wn = wid & 3;
  const int l15 = lane & 15, l4 = lane >> 4;
  const int lx = (lane & 7) << 4;

  const int NT = K >> 6;
  const int niter = NT >> 1;

  int aoff0, aoff1, boff0, boff1;
  #pragma unroll
  for (int i = 0; i < 2; ++i) {
    const int p = i * 8192 + tid * 16;
    const int l = p ^ (((p >> 7) & 7) << 4);
    const int r = p >> 7;
    const int kb = l & 127;
    const int av = ((r >> 6) * 128 + (r & 63)) * lda + (kb >> 1);
    const int bv = ((r >> 5) * 64 + (r & 31)) * ldb + (kb >> 1);
    if (i == 0) { aoff0 = av; boff0 = bv; } else { aoff1 = av; boff1 = bv; }
  }

  int arb[2], brb[2];
  #pragma unroll
  for (int ks = 0; ks < 2; ++ks) {
    arb[ks] = ((((wm * 64 + l15) * 64 + l4 * 8) * 2) + ks * 64) ^ lx;
    brb[ks] = ((((wn * 32 + l15) * 64 + l4 * 8) * 2) + ks * 64) ^ lx;
  }

  f32x4 acc[8][4] = {};
  bf16x8 a0[4][2], a1[4][2], b0[2][2], b1[2][2];

  STAGE_B(0, 0, 0); STAGE_A(0, 0, 0); STAGE_A(0, 1, 0); STAGE_B(0, 1, 0);
  STAGE_B(1, 0, 1); STAGE_A(1, 0, 1);
  asm volatile("s_waitcnt vmcnt(4)" ::: "memory");
  __builtin_amdgcn_s_barrier();

  for (int it = 0; it < niter; ++it) {
    const int tt = it * 2;
    DSREAD_A(a0, 0, 0); DSREAD_B(b0, 0, 0);
    STAGE_A(1, 1, tt + 1);
    BARRIER_MFMA(a0, b0, 0, 0);
    DSREAD_A(a1, 0, 1);
    STAGE_B(1, 1, tt + 1);
    BARRIER_MFMA(a1, b0, 1, 0);
    DSREAD_B(b1, 0, 1);
    STAGE_B(0, 0, tt + 2);
    BARRIER_MFMA(a0, b1, 0, 1);
    STAGE_A(0, 0, tt + 2);
    asm volatile("s_waitcnt vmcnt(4)" ::: "memory");
    BARRIER_MFMA(a1, b1, 1, 1);
    DSREAD_A(a0, 1, 0); DSREAD_B(b0, 1, 0);
    STAGE_A(0, 1, tt + 2);
    BARRIER_MFMA(a0, b0, 0, 0);
    DSREAD_A(a1, 1, 1);
    STAGE_B(0, 1, tt + 2);
    BARRIER_MFMA(a1, b0, 1, 0);
    DSREAD_B(b1, 1, 1);
    STAGE_B(1, 0, tt + 3);
    BARRIER_MFMA(a0, b1, 0, 1);
    STAGE_A(1, 0, tt + 3);
    asm volatile("s_waitcnt vmcnt(4)" ::: "memory");
    BARRIER_MFMA(a1, b1, 1, 1);
  }

  const int cr = l4 * 4;
  __bf16* C = (__bf16*)Cout + (size_t)bz * strideC;
  #pragma unroll
  for (int m = 0; m < 8; ++m) {
    #pragma unroll
    for (int n = 0; n < 4; ++n) {
      const long row = brow + wm * 128 + m * 16 + cr;
      const long col = bcol + wn * 64 + n * 16 + l15;
      #pragma unroll
      for (int e = 0; e < 4; ++e)
        C[(row + e) * (size_t)ldc + col] = (__bf16)__expf(acc[m][n][e] * scale);
    }
  }
}

// ---------------------------------------------------------------------------
// 128x256 4-phase counted-vmcnt GEMM. BK=64, 8 waves (2M x 4N), per-wave 64x64
// (32 cols in each B-half). LDS 96 KiB dbuf, same XOR row-swizzle.
// Per phase: stage -> vmcnt(6) -> ds_read -> barrier/lgkm0/MFMA/barrier.
// Covering vmcnt for every read is one phase earlier + barrier (cross-wave safe).
// EPI: 0 = +bias -> bf16 (proj), 2 = rowsum-normalize -> fp32 (PV)
// ---------------------------------------------------------------------------

#define A2_OFF(BUF)      ((BUF) * 16384)
#define B2_OFF(BUF, NH)  (32768 + ((BUF)*2 + (NH)) * 16384)

#define STAGE_SA(BUF, T) do { int t_ = (T); if (t_ >= NT) t_ = 0;              \
  const __bf16* gA_ = Ablk + (size_t)t_ * 64;                                   \
  gload_lds16(gA_ + aoff0, smem + A2_OFF(BUF) + tid * 16);                      \
  gload_lds16(gA_ + aoff1, smem + A2_OFF(BUF) + 8192 + tid * 16);               \
  const __bf16* gB_ = Bblk + (size_t)t_ * 64;                                   \
  gload_lds16(gB_ + boff0, smem + B2_OFF(BUF, 0) + tid * 16);                   \
  gload_lds16(gB_ + boff1, smem + B2_OFF(BUF, 0) + 8192 + tid * 16); } while (0)

#define STAGE_SB(BUF, T) do { int t_ = (T); if (t_ >= NT) t_ = 0;              \
  const __bf16* gB_ = Bblk + (size_t)(128 * (size_t)ldb) + (size_t)t_ * 64;     \
  gload_lds16(gB_ + boff0, smem + B2_OFF(BUF, 1) + tid * 16);                   \
  gload_lds16(gB_ + boff1, smem + B2_OFF(BUF, 1) + 8192 + tid * 16); } while (0)

#define DSREAD_A2(BUF)                                                          \
  _Pragma("unroll") for (int mi = 0; mi < 4; ++mi) {                            \
    _Pragma("unroll") for (int ks = 0; ks < 2; ++ks)                            \
      af[mi][ks] = *(const bf16x8*)(smem + A2_OFF(BUF) + ara[ks] + mi * 2048); }

#define DSREAD_B2(DST, BUF, NH)                                                 \
  _Pragma("unroll") for (int ni = 0; ni < 2; ++ni) {                            \
    _Pragma("unroll") for (int ks = 0; ks < 2; ++ks)                            \
      DST[ni][ks] = *(const bf16x8*)(smem + B2_OFF(BUF, NH) + brb2[ks] + ni * 2048); }

#define MFMA2(BF, NH, DOSUM) do {                                               \
  __builtin_amdgcn_s_barrier();                                                 \
  asm volatile("s_waitcnt lgkmcnt(0)" ::: "memory");                            \
  __builtin_amdgcn_sched_barrier(0);                                            \
  __builtin_amdgcn_s_setprio(1);                                                \
  _Pragma("unroll") for (int mi = 0; mi < 4; ++mi)                              \
  _Pragma("unroll") for (int ni = 0; ni < 2; ++ni)                              \
  _Pragma("unroll") for (int ks = 0; ks < 2; ++ks)                              \
    acc[mi][(NH)*2+ni] = __builtin_amdgcn_mfma_f32_16x16x32_bf16(               \
        af[mi][ks], BF[ni][ks], acc[mi][(NH)*2+ni], 0, 0, 0);                   \
  if constexpr (EPI == 2) { if (DOSUM) {                                        \
    _Pragma("unroll") for (int mi = 0; mi < 4; ++mi)                            \
    _Pragma("unroll") for (int ks = 0; ks < 2; ++ks)                            \
      accs[mi] = __builtin_amdgcn_mfma_f32_16x16x32_bf16(                       \
          af[mi][ks], onesf, accs[mi], 0, 0, 0); } }                            \
  __builtin_amdgcn_s_setprio(0);                                                \
  __builtin_amdgcn_sched_barrier(0);                                            \
  __builtin_amdgcn_s_barrier(); } while (0)

template <int EPI>
__global__ __launch_bounds__(512) void gemm128_kernel(
    const __bf16* __restrict__ A, const __bf16* __restrict__ B,
    const float* __restrict__ bias, void* __restrict__ Cout,
    int K, int lda, int ldb, int ldc,
    long strideA, long strideB, long strideC)
{
  extern __shared__ char smem[];

  const int gx = gridDim.x, gy = gridDim.y;
  const int nwg = gx * gy * gridDim.z;
  int lin = blockIdx.x + gx * (blockIdx.y + gy * blockIdx.z);
  const int cpx = nwg >> 3;
  int swz = (lin & 7) * cpx + (lin >> 3);
  const int bx = swz % gx;
  int rem = swz / gx;
  const int by = rem % gy;
  const int bz = rem / gy;

  const long brow = (long)by * 128, bcol = (long)bx * 256;
  const __bf16* Ablk = A + (size_t)bz * strideA + (size_t)brow * lda;
  const __bf16* Bblk = B + (size_t)bz * strideB + (size_t)bcol * ldb;

  const int tid  = threadIdx.x;
  const int lane = tid & 63;
  const int wid  = tid >> 6;
  const int wm = wid >> 2, wn = wid & 3;
  const int l15 = lane & 15, l4 = lane >> 4;
  const int lx = (lane & 7) << 4;

  const int NT = K >> 6;
  const int niter = NT >> 1;

  // staging source offsets: region [128 rows][64 k], inverse-swizzled
  int aoff0, aoff1, boff0, boff1;
  #pragma unroll
  for (int i = 0; i < 2; ++i) {
    const int p = i * 8192 + tid * 16;
    const int r = p >> 7;
    const int kb = (p ^ ((r & 7) << 4)) & 127;
    const int av = r * lda + (kb >> 1);
    const int bv = r * ldb + (kb >> 1);
    if (i == 0) { aoff0 = av; boff0 = bv; } else { aoff1 = av; boff1 = bv; }
  }

  int ara[2], brb2[2];
  #pragma unroll
  for (int ks = 0; ks < 2; ++ks) {
    ara[ks]  = ((((wm * 64 + l15) * 64 + l4 * 8) * 2) + ks * 64) ^ lx;
    brb2[ks] = ((((wn * 32 + l15) * 64 + l4 * 8) * 2) + ks * 64) ^ lx;
  }

  f32x4 acc[4][4] = {};
  f32x4 accs[4] = {};
  bf16x8 af[4][2], b0[2][2], b1[2][2];
  bf16x8 onesf;
  #pragma unroll
  for (int j = 0; j < 8; ++j) onesf[j] = (__bf16)1.0f;

  // prologue: S_a(0), S_b(0), S_a(1); vmcnt(6) lands S_a(0)
  STAGE_SA(0, 0); STAGE_SB(0, 0); STAGE_SA(1, 1);
  asm volatile("s_waitcnt vmcnt(6)" ::: "memory");
  __builtin_amdgcn_s_barrier();

  for (int it = 0; it < niter; ++it) {
    const int tt = it * 2;
    // P1: read buf0 {A, B-NH0}; stage S_b(tt+1); vmcnt lands S_b(tt)
    STAGE_SB(1, tt + 1);
    asm volatile("s_waitcnt vmcnt(6)" ::: "memory");
    DSREAD_A2(0); DSREAD_B2(b0, 0, 0);
    MFMA2(b0, 0, 1);
    // P2: read buf0 {B-NH1}; stage S_a(tt+2); vmcnt lands S_a(tt+1)
    STAGE_SA(0, tt + 2);
    asm volatile("s_waitcnt vmcnt(6)" ::: "memory");
    DSREAD_B2(b1, 0, 1);
    MFMA2(b1, 1, 0);
    // P3: read buf1 {A, B-NH0}; stage S_b(tt+2); vmcnt lands S_b(tt+1)
    STAGE_SB(0, tt + 2);
    asm volatile("s_waitcnt vmcnt(6)" ::: "memory");
    DSREAD_A2(1); DSREAD_B2(b0, 1, 0);
    MFMA2(b0, 0, 1);
    // P4: read buf1 {B-NH1}; stage S_a(tt+3); vmcnt lands S_a(tt+2)
    STAGE_SA(1, tt + 3);
    asm volatile("s_waitcnt vmcnt(6)" ::: "memory");
    DSREAD_B2(b1, 1, 1);
    MFMA2(b1, 1, 0);
  }

  // epilogue
  if constexpr (EPI == 2) {
    float* C = (float*)Cout + (size_t)bz * strideC;
    #pragma unroll
    for (int mi = 0; mi < 4; ++mi) {
      f32x4 inv;
      #pragma unroll
      for (int e = 0; e < 4; ++e) inv[e] = 1.0f / accs[mi][e];
      #pragma unroll
      for (int n = 0; n < 4; ++n) {
        const long row = brow + wm * 64 + mi * 16 + l4 * 4;
        const long col = bcol + (n >> 1) * 128 + wn * 32 + (n & 1) * 16 + l15;
        #pragma unroll
        for (int e = 0; e < 4; ++e)
          C[(row + e) * (size_t)ldc + col] = acc[mi][n][e] * inv[e];
      }
    }
  } else {
    __bf16* C = (__bf16*)Cout + (size_t)bz * strideC;
    #pragma unroll
    for (int mi = 0; mi < 4; ++mi) {
      #pragma unroll
      for (int n = 0; n < 4; ++n) {
        const long row = brow + wm * 64 + mi * 16 + l4 * 4;
        const long col = bcol + (n >> 1) * 128 + wn * 32 + (n & 1) * 16 + l15;
        const float bvv = bias[bz * DD + col];
        #pragma unroll
        for (int e = 0; e < 4; ++e)
          C[(row + e) * (size_t)ldc + col] = (__bf16)(acc[mi][n][e] + bvv);
      }
    }
  }
}

extern "C" void kernel_launch(void* const* d_in, const int* in_sizes, int n_in,
                              void* d_out, int out_size, void* d_ws, size_t ws_size,
                              hipStream_t stream)
{
  const float* query = (const float*)d_in[0];
  const float* key   = (const float*)d_in[1];
  const float* value = (const float*)d_in[2];
  const float* wq = (const float*)d_in[3];
  const float* bq = (const float*)d_in[4];
  const float* wk = (const float*)d_in[5];
  const float* bk = (const float*)d_in[6];
  const float* wv = (const float*)d_in[7];
  const float* bv = (const float*)d_in[8];

  char* ws = (char*)d_ws;
  __bf16* Xbf     = (__bf16*)(ws + 0);           // 50,331,648 B
  __bf16* Wt      = (__bf16*)(ws + 50331648);    //  6,291,456 B
  float*  biasbuf = (float*)(ws + 56623104);     //     12,288 B
  __bf16* Qb      = (__bf16*)(ws + 56635392);    // 16,777,216 B
  __bf16* Kb      = (__bf16*)(ws + 73412608);    // 16,777,216 B
  __bf16* Vb      = (__bf16*)(ws + 90189824);    // 16,777,216 B (end 106,967,040)
  __bf16* P       = Xbf;   // alias: X dead after projections
  __bf16* Vt      = Qb;    // alias: Q dead after scores GEMM

  hipFuncSetAttribute((const void*)gemm8p_kernel<1>, hipFuncAttributeMaxDynamicSharedMemorySize, 131072);
  hipFuncSetAttribute((const void*)gemm128_kernel<0>, hipFuncAttributeMaxDynamicSharedMemorySize, 131072);
  hipFuncSetAttribute((const void*)gemm128_kernel<2>, hipFuncAttributeMaxDynamicSharedMemorySize, 131072);

  dim3 b256(256), b512(512);

  cvt_in_kernel<<<dim3(8192, 1, 3), b256, 0, stream>>>(query, key, value, Xbf);
  prep_w_kernel<<<dim3(32, 32, 3), b256, 0, stream>>>(wq, wk, wv, bq, bk, bv, Wt, biasbuf);

  // projections: [8192,1024] = X @ Wt^T + bias  (z = q/k/v), grid 4x64x3 = 768 = 3 exact rounds
  gemm128_kernel<0><<<dim3(4, 64, 3), b512, 98304, stream>>>(
      Xbf, Wt, biasbuf, Qb,
      1024, 1024, 1024, 1024,
      8388608L, 1048576L, 8388608L);
  // scores: P[b] = exp(Q[b] @ K[b]^T / 32) -> bf16 (unnormalized), grid 8x8x4 = 256
  gemm8p_kernel<1><<<dim3(8, 8, 4), b512, 131072, stream>>>(
      Qb, Kb, 0.03125f, P,
      1024, 1024, 1024, 2048,
      2097152L, 2097152L, 4194304L);

  transpose_v_kernel<<<dim3(32, 64, 4), b256, 0, stream>>>(Vb, Vt);

  // out[b] = (P[b] @ Vt[b]^T) / rowsum(P[b]) -> fp32, grid 4x16x4 = 256 = 1 exact round
  gemm128_kernel<2><<<dim3(4, 16, 4), b512, 98304, stream>>>(
      P, Vt, nullptr, d_out,
      2048, 2048, 2048, 1024,
      4194304L, 2097152L, 2097152L);

  (void)in_sizes; (void)n_in; (void)out_size; (void)ws_size;
}

// Round 4
// 172.173 us; speedup vs baseline: 1.4607x; 1.0577x over previous
//
#include <hip/hip_runtime.h>
#include <hip/hip_bf16.h>

typedef __attribute__((ext_vector_type(4))) float   f32x4;
typedef __attribute__((ext_vector_type(8))) __bf16  bf16x8;
typedef __attribute__((ext_vector_type(4))) __bf16  bf16x4;

#define NB 4
#define SS 2048
#define DD 1024

__device__ __forceinline__ void gload_lds16(const void* g, void* l) {
  __builtin_amdgcn_global_load_lds((const __attribute__((address_space(1))) void*)g,
                                   (__attribute__((address_space(3))) void*)l,
                                   16, 0, 0);
}

// W[k][n] fp32 -> Wt[n][k] bf16 (transpose+convert); also copy biases. grid (32,32,3) x 256
__global__ __launch_bounds__(256) void prep_w_kernel(
    const float* __restrict__ wq, const float* __restrict__ wk, const float* __restrict__ wv,
    const float* __restrict__ bq, const float* __restrict__ bk, const float* __restrict__ bv,
    __bf16* __restrict__ Wt, float* __restrict__ biasbuf)
{
  const int z = blockIdx.z;
  const float* W  = z == 0 ? wq : (z == 1 ? wk : wv);
  const float* bi = z == 0 ? bq : (z == 1 ? bk : bv);
  __bf16* dst = Wt + (size_t)z * (size_t)(DD * DD);
  const int n0 = blockIdx.x * 32, k0 = blockIdx.y * 32;
  __shared__ float t[32][33];
  const int tx = threadIdx.x & 31, ty = threadIdx.x >> 5;
  #pragma unroll
  for (int i = 0; i < 4; i++)
    t[ty + 8 * i][tx] = W[(size_t)(k0 + ty + 8 * i) * DD + n0 + tx];
  __syncthreads();
  #pragma unroll
  for (int i = 0; i < 4; i++)
    dst[(size_t)(n0 + ty + 8 * i) * DD + k0 + tx] = (__bf16)t[tx][ty + 8 * i];
  if (blockIdx.x == 0 && blockIdx.y == 0) {
    #pragma unroll
    for (int i = 0; i < 4; i++)
      biasbuf[z * DD + threadIdx.x + 256 * i] = bi[threadIdx.x + 256 * i];
  }
}

// ---------------------------------------------------------------------------
// Shared LDS region layout for 128x256 kernels (96 KiB):
// A: 2 buf x 16 KiB, B: 2 buf x 2 halves x 16 KiB
// ---------------------------------------------------------------------------
#define A2_OFF(BUF)      ((BUF) * 16384)
#define B2_OFF(BUF, NH)  (32768 + ((BUF)*2 + (NH)) * 16384)

#define DSREAD_A2(BUF)                                                          \
  _Pragma("unroll") for (int mi = 0; mi < 4; ++mi) {                            \
    _Pragma("unroll") for (int ks = 0; ks < 2; ++ks)                            \
      af[mi][ks] = *(const bf16x8*)(smem + A2_OFF(BUF) + ara[ks] + mi * 2048); }

#define DSREAD_B2(DST, BUF, NH)                                                 \
  _Pragma("unroll") for (int ni = 0; ni < 2; ++ni) {                            \
    _Pragma("unroll") for (int ks = 0; ks < 2; ++ks)                            \
      DST[ni][ks] = *(const bf16x8*)(smem + B2_OFF(BUF, NH) + brb2[ks] + ni * 2048); }

// ---------------------------------------------------------------------------
// Projection kernel: [8192,1024](bf16 out) = X(fp32!) @ Wt^T + bias, z = q/k/v.
// A is reg-staged (fp32 load -> cvt -> ds_write, T14 split); B via global_load_lds.
// z==2 writes V TRANSPOSED: Vt[b][d][s].
// 128x256 tile, BK=64, 8 waves (2M x 4N), 4-phase counted-vmcnt schedule.
// ---------------------------------------------------------------------------

#define PJ_GLA(V0, V1, V2, V3, T) do { int t_ = (T); if (t_ >= 16) t_ = 0;      \
  const float* g_ = Ablk + (size_t)t_ * 64;                                     \
  V0 = *(const float4*)(g_ + aoffF0); V1 = *(const float4*)(g_ + aoffF0 + 4);   \
  V2 = *(const float4*)(g_ + aoffF1); V3 = *(const float4*)(g_ + aoffF1 + 4);   \
  __builtin_amdgcn_sched_barrier(0); } while (0)

#define PJ_WRA(BUF, V0, V1, V2, V3) do {                                        \
  bf16x8 w0_, w1_;                                                              \
  w0_[0]=(__bf16)V0.x; w0_[1]=(__bf16)V0.y; w0_[2]=(__bf16)V0.z; w0_[3]=(__bf16)V0.w; \
  w0_[4]=(__bf16)V1.x; w0_[5]=(__bf16)V1.y; w0_[6]=(__bf16)V1.z; w0_[7]=(__bf16)V1.w; \
  w1_[0]=(__bf16)V2.x; w1_[1]=(__bf16)V2.y; w1_[2]=(__bf16)V2.z; w1_[3]=(__bf16)V2.w; \
  w1_[4]=(__bf16)V3.x; w1_[5]=(__bf16)V3.y; w1_[6]=(__bf16)V3.z; w1_[7]=(__bf16)V3.w; \
  *(bf16x8*)(smem + A2_OFF(BUF) + tid * 16) = w0_;                              \
  *(bf16x8*)(smem + A2_OFF(BUF) + 8192 + tid * 16) = w1_; } while (0)

#define PJ_SB0(BUF, T) do { int t_ = (T); if (t_ >= 16) t_ = 0;                 \
  const __bf16* gB_ = Bblk + (size_t)t_ * 64;                                   \
  gload_lds16(gB_ + boff0, smem + B2_OFF(BUF, 0) + tid * 16);                   \
  gload_lds16(gB_ + boff1, smem + B2_OFF(BUF, 0) + 8192 + tid * 16); } while (0)

#define PJ_SB1(BUF, T) do { int t_ = (T); if (t_ >= 16) t_ = 0;                 \
  const __bf16* gB_ = Bblk + (size_t)(128 * 1024) + (size_t)t_ * 64;            \
  gload_lds16(gB_ + boff0, smem + B2_OFF(BUF, 1) + tid * 16);                   \
  gload_lds16(gB_ + boff1, smem + B2_OFF(BUF, 1) + 8192 + tid * 16); } while (0)

#define PJ_MFMA(BF, NH) do {                                                    \
  __builtin_amdgcn_s_barrier();                                                 \
  asm volatile("s_waitcnt lgkmcnt(0)" ::: "memory");                            \
  __builtin_amdgcn_sched_barrier(0);                                            \
  __builtin_amdgcn_s_setprio(1);                                                \
  _Pragma("unroll") for (int mi = 0; mi < 4; ++mi)                              \
  _Pragma("unroll") for (int ni = 0; ni < 2; ++ni)                              \
  _Pragma("unroll") for (int ks = 0; ks < 2; ++ks)                              \
    acc[mi][(NH)*2+ni] = __builtin_amdgcn_mfma_f32_16x16x32_bf16(               \
        af[mi][ks], BF[ni][ks], acc[mi][(NH)*2+ni], 0, 0, 0);                   \
  __builtin_amdgcn_s_setprio(0);                                                \
  __builtin_amdgcn_sched_barrier(0);                                            \
  __builtin_amdgcn_s_barrier(); } while (0)

__global__ __launch_bounds__(512) void proj_kernel(
    const float* __restrict__ Xq, const float* __restrict__ Xk, const float* __restrict__ Xv,
    const __bf16* __restrict__ Wt, const float* __restrict__ bias,
    __bf16* __restrict__ Qo, __bf16* __restrict__ Ko, __bf16* __restrict__ Vt)
{
  extern __shared__ char smem[];

  const int gx = gridDim.x, gy = gridDim.y;
  const int nwg = gx * gy * gridDim.z;
  int lin = blockIdx.x + gx * (blockIdx.y + gy * blockIdx.z);
  const int cpx = nwg >> 3;
  int swz = (lin & 7) * cpx + (lin >> 3);
  const int bx = swz % gx;
  int rem = swz / gx;
  const int by = rem % gy;
  const int bz = rem / gy;

  const long brow = (long)by * 128, bcol = (long)bx * 256;
  const float* Xsel = bz == 0 ? Xq : (bz == 1 ? Xk : Xv);
  const float* Ablk = Xsel + (size_t)brow * 1024;
  const __bf16* Bblk = Wt + (size_t)bz * (DD * DD) + (size_t)bcol * 1024;

  const int tid  = threadIdx.x;
  const int lane = tid & 63;
  const int wid  = tid >> 6;
  const int wm = wid >> 2, wn = wid & 3;
  const int l15 = lane & 15, l4 = lane >> 4;
  const int lx = (lane & 7) << 4;

  const int niter = 8;  // K=1024, NT=16

  // source offsets for physical LDS byte ranges (inverse-swizzled)
  int aoffF0, aoffF1, boff0, boff1;
  #pragma unroll
  for (int i = 0; i < 2; ++i) {
    const int p = i * 8192 + tid * 16;
    const int r = p >> 7;
    const int kb = (p ^ ((r & 7) << 4)) & 127;
    const int aF = r * 1024 + (kb >> 1);   // fp32 elements
    const int bO = r * 1024 + (kb >> 1);   // bf16 elements
    if (i == 0) { aoffF0 = aF; boff0 = bO; } else { aoffF1 = aF; boff1 = bO; }
  }

  int ara[2], brb2[2];
  #pragma unroll
  for (int ks = 0; ks < 2; ++ks) {
    ara[ks]  = ((((wm * 64 + l15) * 64 + l4 * 8) * 2) + ks * 64) ^ lx;
    brb2[ks] = ((((wn * 32 + l15) * 64 + l4 * 8) * 2) + ks * 64) ^ lx;
  }

  f32x4 acc[4][4] = {};
  bf16x8 af[4][2], b0[2][2], b1[2][2];
  float4 La0, La1, La2, La3, Lb0, Lb1, Lb2, Lb3;

  // prologue: glA(0) [4]; B0/B1->buf0(0), B0->buf1(1) [6]; glA(1) [4]
  PJ_GLA(La0, La1, La2, La3, 0);
  PJ_SB0(0, 0); PJ_SB1(0, 0); PJ_SB0(1, 1);
  PJ_GLA(Lb0, Lb1, Lb2, Lb3, 1);
  asm volatile("s_waitcnt vmcnt(10)" ::: "memory");   // land glA(0)
  PJ_WRA(0, La0, La1, La2, La3);
  asm volatile("s_waitcnt vmcnt(0)" ::: "memory");    // land everything else
  PJ_WRA(1, Lb0, Lb1, Lb2, Lb3);
  asm volatile("s_waitcnt lgkmcnt(0)" ::: "memory");
  __builtin_amdgcn_s_barrier();

  for (int it = 0; it < niter; ++it) {
    const int tt = it * 2;
    // P1: reads buf0{A,B0}(tt); issue glA(tt+2), B1->buf1(tt+1)
    PJ_GLA(La0, La1, La2, La3, tt + 2);
    PJ_SB1(1, tt + 1);
    DSREAD_A2(0); DSREAD_B2(b0, 0, 0);
    PJ_MFMA(b0, 0);
    // P2: reads buf0{B1}(tt); land glA(tt+2), write buf0-A, issue B0->buf0(tt+2)
    asm volatile("s_waitcnt vmcnt(2)" ::: "memory");
    PJ_WRA(0, La0, La1, La2, La3);
    PJ_SB0(0, tt + 2);
    DSREAD_B2(b1, 0, 1);
    PJ_MFMA(b1, 1);
    // P3: reads buf1{A,B0}(tt+1); issue glA(tt+3), B1->buf0(tt+2)
    PJ_GLA(Lb0, Lb1, Lb2, Lb3, tt + 3);
    PJ_SB1(0, tt + 2);
    DSREAD_A2(1); DSREAD_B2(b0, 1, 0);
    PJ_MFMA(b0, 0);
    // P4: reads buf1{B1}(tt+1); land glA(tt+3), write buf1-A, issue B0->buf1(tt+3)
    asm volatile("s_waitcnt vmcnt(2)" ::: "memory");
    PJ_WRA(1, Lb0, Lb1, Lb2, Lb3);
    PJ_SB0(1, tt + 3);
    DSREAD_B2(b1, 1, 1);
    PJ_MFMA(b1, 1);
  }

  // epilogue
  if (bz == 2) {
    // V transposed: Vt[b][d][s], d = col, s = row (within batch)
    #pragma unroll
    for (int mi = 0; mi < 4; ++mi) {
      #pragma unroll
      for (int n = 0; n < 4; ++n) {
        const long row = brow + wm * 64 + mi * 16 + l4 * 4;
        const long col = bcol + (n >> 1) * 128 + wn * 32 + (n & 1) * 16 + l15;
        const float bvv = bias[2 * DD + col];
        const long bb = row >> 11, s = row & 2047;
        bf16x4 pk = { (__bf16)(acc[mi][n][0] + bvv), (__bf16)(acc[mi][n][1] + bvv),
                      (__bf16)(acc[mi][n][2] + bvv), (__bf16)(acc[mi][n][3] + bvv) };
        *(bf16x4*)&Vt[bb * 2097152 + col * 2048 + s] = pk;
      }
    }
  } else {
    __bf16* C = bz == 0 ? Qo : Ko;
    #pragma unroll
    for (int mi = 0; mi < 4; ++mi) {
      #pragma unroll
      for (int n = 0; n < 4; ++n) {
        const long row = brow + wm * 64 + mi * 16 + l4 * 4;
        const long col = bcol + (n >> 1) * 128 + wn * 32 + (n & 1) * 16 + l15;
        const float bvv = bias[bz * DD + col];
        #pragma unroll
        for (int e = 0; e < 4; ++e)
          C[(row + e) * 1024 + col] = (__bf16)(acc[mi][n][e] + bvv);
      }
    }
  }
}

// ---------------------------------------------------------------------------
// 256x256 8-phase counted-vmcnt GEMM (scores): P = exp(Q @ K^T * scale) -> bf16
// ---------------------------------------------------------------------------

#define A_OFF(BUF, MH) (((BUF)*2 + (MH)) * 16384)
#define B_OFF(BUF, NH) (65536 + ((BUF)*2 + (NH)) * 16384)

#define STAGE_A(BUF, MH, T) do { int t_ = (T); if (t_ >= NT) t_ = 0;            \
  const __bf16* gs_ = Ablk + (size_t)(MH) * (64 * (size_t)lda) + (size_t)t_ * 64; \
  gload_lds16(gs_ + aoff0, smem + A_OFF(BUF, MH) + tid * 16);                    \
  gload_lds16(gs_ + aoff1, smem + A_OFF(BUF, MH) + 8192 + tid * 16); } while (0)

#define STAGE_B(BUF, NH, T) do { int t_ = (T); if (t_ >= NT) t_ = 0;            \
  const __bf16* gs_ = Bblk + (size_t)(NH) * (32 * (size_t)ldb) + (size_t)t_ * 64; \
  gload_lds16(gs_ + boff0, smem + B_OFF(BUF, NH) + tid * 16);                    \
  gload_lds16(gs_ + boff1, smem + B_OFF(BUF, NH) + 8192 + tid * 16); } while (0)

#define DSREAD_A(DST, BUF, MH)                                                  \
  _Pragma("unroll") for (int mi = 0; mi < 4; ++mi) {                            \
    _Pragma("unroll") for (int ks = 0; ks < 2; ++ks)                            \
      DST[mi][ks] = *(const bf16x8*)(smem + A_OFF(BUF, MH) + arb[ks] + mi * 2048); }

#define DSREAD_B(DST, BUF, NH)                                                  \
  _Pragma("unroll") for (int ni = 0; ni < 2; ++ni) {                            \
    _Pragma("unroll") for (int ks = 0; ks < 2; ++ks)                            \
      DST[ni][ks] = *(const bf16x8*)(smem + B_OFF(BUF, NH) + brb[ks] + ni * 2048); }

#define BARRIER_MFMA(AF, BF, MH, NH) do {                                       \
  __builtin_amdgcn_s_barrier();                                                 \
  asm volatile("s_waitcnt lgkmcnt(0)" ::: "memory");                            \
  __builtin_amdgcn_sched_barrier(0);                                            \
  __builtin_amdgcn_s_setprio(1);                                                \
  _Pragma("unroll") for (int mi = 0; mi < 4; ++mi)                              \
  _Pragma("unroll") for (int ni = 0; ni < 2; ++ni)                              \
  _Pragma("unroll") for (int ks = 0; ks < 2; ++ks)                              \
    acc[(MH)*4+mi][(NH)*2+ni] = __builtin_amdgcn_mfma_f32_16x16x32_bf16(        \
        AF[mi][ks], BF[ni][ks], acc[(MH)*4+mi][(NH)*2+ni], 0, 0, 0);            \
  __builtin_amdgcn_s_setprio(0);                                                \
  __builtin_amdgcn_sched_barrier(0);                                            \
  __builtin_amdgcn_s_barrier(); } while (0)

__global__ __launch_bounds__(512) void gemm8p_kernel(
    const __bf16* __restrict__ A, const __bf16* __restrict__ B,
    float scale, void* __restrict__ Cout,
    int K, int lda, int ldb, int ldc,
    long strideA, long strideB, long strideC)
{
  extern __shared__ char smem[];

  const int gx = gridDim.x, gy = gridDim.y;
  const int nwg = gx * gy * gridDim.z;
  int lin = blockIdx.x + gx * (blockIdx.y + gy * blockIdx.z);
  const int cpx = nwg >> 3;
  int swz = (lin & 7) * cpx + (lin >> 3);
  const int bx = swz % gx;
  int rem = swz / gx;
  const int by = rem % gy;
  const int bz = rem / gy;

  const long brow = (long)by * 256, bcol = (long)bx * 256;
  const __bf16* Ablk = A + (size_t)bz * strideA + (size_t)brow * lda;
  const __bf16* Bblk = B + (size_t)bz * strideB + (size_t)bcol * ldb;

  const int tid  = threadIdx.x;
  const int lane = tid & 63;
  const int wid  = tid >> 6;
  const int wm = wid >> 2, wn = wid & 3;
  const int l15 = lane & 15, l4 = lane >> 4;
  const int lx = (lane & 7) << 4;

  const int NT = K >> 6;
  const int niter = NT >> 1;

  int aoff0, aoff1, boff0, boff1;
  #pragma unroll
  for (int i = 0; i < 2; ++i) {
    const int p = i * 8192 + tid * 16;
    const int l = p ^ (((p >> 7) & 7) << 4);
    const int r = p >> 7;
    const int kb = l & 127;
    const int av = ((r >> 6) * 128 + (r & 63)) * lda + (kb >> 1);
    const int bv = ((r >> 5) * 64 + (r & 31)) * ldb + (kb >> 1);
    if (i == 0) { aoff0 = av; boff0 = bv; } else { aoff1 = av; boff1 = bv; }
  }

  int arb[2], brb[2];
  #pragma unroll
  for (int ks = 0; ks < 2; ++ks) {
    arb[ks] = ((((wm * 64 + l15) * 64 + l4 * 8) * 2) + ks * 64) ^ lx;
    brb[ks] = ((((wn * 32 + l15) * 64 + l4 * 8) * 2) + ks * 64) ^ lx;
  }

  f32x4 acc[8][4] = {};
  bf16x8 a0[4][2], a1[4][2], b0[2][2], b1[2][2];

  STAGE_B(0, 0, 0); STAGE_A(0, 0, 0); STAGE_A(0, 1, 0); STAGE_B(0, 1, 0);
  STAGE_B(1, 0, 1); STAGE_A(1, 0, 1);
  asm volatile("s_waitcnt vmcnt(4)" ::: "memory");
  __builtin_amdgcn_s_barrier();

  for (int it = 0; it < niter; ++it) {
    const int tt = it * 2;
    DSREAD_A(a0, 0, 0); DSREAD_B(b0, 0, 0);
    STAGE_A(1, 1, tt + 1);
    BARRIER_MFMA(a0, b0, 0, 0);
    DSREAD_A(a1, 0, 1);
    STAGE_B(1, 1, tt + 1);
    BARRIER_MFMA(a1, b0, 1, 0);
    DSREAD_B(b1, 0, 1);
    STAGE_B(0, 0, tt + 2);
    BARRIER_MFMA(a0, b1, 0, 1);
    STAGE_A(0, 0, tt + 2);
    asm volatile("s_waitcnt vmcnt(4)" ::: "memory");
    BARRIER_MFMA(a1, b1, 1, 1);
    DSREAD_A(a0, 1, 0); DSREAD_B(b0, 1, 0);
    STAGE_A(0, 1, tt + 2);
    BARRIER_MFMA(a0, b0, 0, 0);
    DSREAD_A(a1, 1, 1);
    STAGE_B(0, 1, tt + 2);
    BARRIER_MFMA(a1, b0, 1, 0);
    DSREAD_B(b1, 1, 1);
    STAGE_B(1, 0, tt + 3);
    BARRIER_MFMA(a0, b1, 0, 1);
    STAGE_A(1, 0, tt + 3);
    asm volatile("s_waitcnt vmcnt(4)" ::: "memory");
    BARRIER_MFMA(a1, b1, 1, 1);
  }

  const int cr = l4 * 4;
  __bf16* C = (__bf16*)Cout + (size_t)bz * strideC;
  #pragma unroll
  for (int m = 0; m < 8; ++m) {
    #pragma unroll
    for (int n = 0; n < 4; ++n) {
      const long row = brow + wm * 128 + m * 16 + cr;
      const long col = bcol + wn * 64 + n * 16 + l15;
      #pragma unroll
      for (int e = 0; e < 4; ++e)
        C[(row + e) * (size_t)ldc + col] = (__bf16)__expf(acc[m][n][e] * scale);
    }
  }
}

// ---------------------------------------------------------------------------
// 128x256 4-phase counted-vmcnt GEMM (PV): out = (P @ Vt^T) / rowsum(P) -> fp32
// ---------------------------------------------------------------------------

#define STAGE_SA(BUF, T) do { int t_ = (T); if (t_ >= NT) t_ = 0;              \
  const __bf16* gA_ = Ablk + (size_t)t_ * 64;                                   \
  gload_lds16(gA_ + aoff0, smem + A2_OFF(BUF) + tid * 16);                      \
  gload_lds16(gA_ + aoff1, smem + A2_OFF(BUF) + 8192 + tid * 16);               \
  const __bf16* gB_ = Bblk + (size_t)t_ * 64;                                   \
  gload_lds16(gB_ + boff0, smem + B2_OFF(BUF, 0) + tid * 16);                   \
  gload_lds16(gB_ + boff1, smem + B2_OFF(BUF, 0) + 8192 + tid * 16); } while (0)

#define STAGE_SB(BUF, T) do { int t_ = (T); if (t_ >= NT) t_ = 0;              \
  const __bf16* gB_ = Bblk + (size_t)(128 * (size_t)ldb) + (size_t)t_ * 64;     \
  gload_lds16(gB_ + boff0, smem + B2_OFF(BUF, 1) + tid * 16);                   \
  gload_lds16(gB_ + boff1, smem + B2_OFF(BUF, 1) + 8192 + tid * 16); } while (0)

#define MFMA2(BF, NH, DOSUM) do {                                               \
  __builtin_amdgcn_s_barrier();                                                 \
  asm volatile("s_waitcnt lgkmcnt(0)" ::: "memory");                            \
  __builtin_amdgcn_sched_barrier(0);                                            \
  __builtin_amdgcn_s_setprio(1);                                                \
  _Pragma("unroll") for (int mi = 0; mi < 4; ++mi)                              \
  _Pragma("unroll") for (int ni = 0; ni < 2; ++ni)                              \
  _Pragma("unroll") for (int ks = 0; ks < 2; ++ks)                              \
    acc[mi][(NH)*2+ni] = __builtin_amdgcn_mfma_f32_16x16x32_bf16(               \
        af[mi][ks], BF[ni][ks], acc[mi][(NH)*2+ni], 0, 0, 0);                   \
  if (DOSUM) {                                                                  \
    _Pragma("unroll") for (int mi = 0; mi < 4; ++mi)                            \
    _Pragma("unroll") for (int ks = 0; ks < 2; ++ks)                            \
      accs[mi] = __builtin_amdgcn_mfma_f32_16x16x32_bf16(                       \
          af[mi][ks], onesf, accs[mi], 0, 0, 0); }                              \
  __builtin_amdgcn_s_setprio(0);                                                \
  __builtin_amdgcn_sched_barrier(0);                                            \
  __builtin_amdgcn_s_barrier(); } while (0)

__global__ __launch_bounds__(512) void gemm128_kernel(
    const __bf16* __restrict__ A, const __bf16* __restrict__ B,
    void* __restrict__ Cout,
    int K, int lda, int ldb, int ldc,
    long strideA, long strideB, long strideC)
{
  extern __shared__ char smem[];

  const int gx = gridDim.x, gy = gridDim.y;
  const int nwg = gx * gy * gridDim.z;
  int lin = blockIdx.x + gx * (blockIdx.y + gy * blockIdx.z);
  const int cpx = nwg >> 3;
  int swz = (lin & 7) * cpx + (lin >> 3);
  const int bx = swz % gx;
  int rem = swz / gx;
  const int by = rem % gy;
  const int bz = rem / gy;

  const long brow = (long)by * 128, bcol = (long)bx * 256;
  const __bf16* Ablk = A + (size_t)bz * strideA + (size_t)brow * lda;
  const __bf16* Bblk = B + (size_t)bz * strideB + (size_t)bcol * ldb;

  const int tid  = threadIdx.x;
  const int lane = tid & 63;
  const int wid  = tid >> 6;
  const int wm = wid >> 2, wn = wid & 3;
  const int l15 = lane & 15, l4 = lane >> 4;
  const int lx = (lane & 7) << 4;

  const int NT = K >> 6;
  const int niter = NT >> 1;

  int aoff0, aoff1, boff0, boff1;
  #pragma unroll
  for (int i = 0; i < 2; ++i) {
    const int p = i * 8192 + tid * 16;
    const int r = p >> 7;
    const int kb = (p ^ ((r & 7) << 4)) & 127;
    const int av = r * lda + (kb >> 1);
    const int bv = r * ldb + (kb >> 1);
    if (i == 0) { aoff0 = av; boff0 = bv; } else { aoff1 = av; boff1 = bv; }
  }

  int ara[2], brb2[2];
  #pragma unroll
  for (int ks = 0; ks < 2; ++ks) {
    ara[ks]  = ((((wm * 64 + l15) * 64 + l4 * 8) * 2) + ks * 64) ^ lx;
    brb2[ks] = ((((wn * 32 + l15) * 64 + l4 * 8) * 2) + ks * 64) ^ lx;
  }

  f32x4 acc[4][4] = {};
  f32x4 accs[4] = {};
  bf16x8 af[4][2], b0[2][2], b1[2][2];
  bf16x8 onesf;
  #pragma unroll
  for (int j = 0; j < 8; ++j) onesf[j] = (__bf16)1.0f;

  STAGE_SA(0, 0); STAGE_SB(0, 0); STAGE_SA(1, 1);
  asm volatile("s_waitcnt vmcnt(6)" ::: "memory");
  __builtin_amdgcn_s_barrier();

  for (int it = 0; it < niter; ++it) {
    const int tt = it * 2;
    STAGE_SB(1, tt + 1);
    asm volatile("s_waitcnt vmcnt(6)" ::: "memory");
    DSREAD_A2(0); DSREAD_B2(b0, 0, 0);
    MFMA2(b0, 0, 1);
    STAGE_SA(0, tt + 2);
    asm volatile("s_waitcnt vmcnt(6)" ::: "memory");
    DSREAD_B2(b1, 0, 1);
    MFMA2(b1, 1, 0);
    STAGE_SB(0, tt + 2);
    asm volatile("s_waitcnt vmcnt(6)" ::: "memory");
    DSREAD_A2(1); DSREAD_B2(b0, 1, 0);
    MFMA2(b0, 0, 1);
    STAGE_SA(1, tt + 3);
    asm volatile("s_waitcnt vmcnt(6)" ::: "memory");
    DSREAD_B2(b1, 1, 1);
    MFMA2(b1, 1, 0);
  }

  float* C = (float*)Cout + (size_t)bz * strideC;
  #pragma unroll
  for (int mi = 0; mi < 4; ++mi) {
    f32x4 inv;
    #pragma unroll
    for (int e = 0; e < 4; ++e) inv[e] = 1.0f / accs[mi][e];
    #pragma unroll
    for (int n = 0; n < 4; ++n) {
      const long row = brow + wm * 64 + mi * 16 + l4 * 4;
      const long col = bcol + (n >> 1) * 128 + wn * 32 + (n & 1) * 16 + l15;
      #pragma unroll
      for (int e = 0; e < 4; ++e)
        C[(row + e) * (size_t)ldc + col] = acc[mi][n][e] * inv[e];
    }
  }
}

extern "C" void kernel_launch(void* const* d_in, const int* in_sizes, int n_in,
                              void* d_out, int out_size, void* d_ws, size_t ws_size,
                              hipStream_t stream)
{
  const float* query = (const float*)d_in[0];
  const float* key   = (const float*)d_in[1];
  const float* value = (const float*)d_in[2];
  const float* wq = (const float*)d_in[3];
  const float* bq = (const float*)d_in[4];
  const float* wk = (const float*)d_in[5];
  const float* bk = (const float*)d_in[6];
  const float* wv = (const float*)d_in[7];
  const float* bv = (const float*)d_in[8];

  char* ws = (char*)d_ws;
  __bf16* P       = (__bf16*)(ws + 0);           // 33,554,432 B
  __bf16* Wt      = (__bf16*)(ws + 33554432);    //  6,291,456 B
  float*  biasbuf = (float*)(ws + 39845888);     //     12,288 B
  __bf16* Qb      = (__bf16*)(ws + 39858176);    // 16,777,216 B
  __bf16* Kb      = (__bf16*)(ws + 56635392);    // 16,777,216 B
  __bf16* Vt      = (__bf16*)(ws + 73412608);    // 16,777,216 B (end 90,189,824)

  hipFuncSetAttribute((const void*)proj_kernel,    hipFuncAttributeMaxDynamicSharedMemorySize, 131072);
  hipFuncSetAttribute((const void*)gemm8p_kernel,  hipFuncAttributeMaxDynamicSharedMemorySize, 131072);
  hipFuncSetAttribute((const void*)gemm128_kernel, hipFuncAttributeMaxDynamicSharedMemorySize, 131072);

  dim3 b256(256), b512(512);

  // weights: transpose+convert; biases: copy
  prep_w_kernel<<<dim3(32, 32, 3), b256, 0, stream>>>(wq, wk, wv, bq, bk, bv, Wt, biasbuf);

  // projections (fused fp32 read + bf16 cvt; V written transposed), 768 blocks
  proj_kernel<<<dim3(4, 64, 3), b512, 98304, stream>>>(
      query, key, value, Wt, biasbuf, Qb, Kb, Vt);

  // scores: P[b] = exp(Q[b] @ K[b]^T / 32) -> bf16 (unnormalized), 256 blocks
  gemm8p_kernel<<<dim3(8, 8, 4), b512, 131072, stream>>>(
      Qb, Kb, 0.03125f, P,
      1024, 1024, 1024, 2048,
      2097152L, 2097152L, 4194304L);

  // out[b] = (P[b] @ Vt[b]^T) / rowsum(P[b]) -> fp32, 256 blocks
  gemm128_kernel<<<dim3(4, 16, 4), b512, 98304, stream>>>(
      P, Vt, d_out,
      2048, 2048, 2048, 1024,
      4194304L, 2097152L, 2097152L);

  (void)in_sizes; (void)n_in; (void)out_size; (void)ws_size;
}